// Round 1
// baseline (789.230 us; speedup 1.0000x reference)
//
#include <hip/hip_runtime.h>
#include <hip/hip_bf16.h>
#include <math.h>

#define BATCH 4
#define HEADS 16
#define SEQ   2048
#define DIM   128
#define BHN   (BATCH*HEADS)

#define BQ 128   // q rows per block
#define WQ 32    // q rows per wave (2 MFMA M-blocks)
#define KT 32    // k rows per stage/compute tile
#define NXB (SEQ/BQ)   // 16 q-blocks per bh

typedef short bf16x8 __attribute__((ext_vector_type(8)));
typedef float f32x4  __attribute__((ext_vector_type(4)));

static __device__ __forceinline__ unsigned short f2bf(float f) {
    union { float f; unsigned u; } x; x.f = f;
    unsigned r = x.u + 0x7FFF + ((x.u >> 16) & 1);  // RNE
    return (unsigned short)(r >> 16);
}

// async 16B global -> LDS (no data VGPRs; LDS dest = wave-uniform base + lane*16)
static __device__ __forceinline__ void async_cp16(const unsigned short* g, unsigned short* l) {
    __builtin_amdgcn_global_load_lds(
        (const __attribute__((address_space(1))) unsigned int*)g,
        (__attribute__((address_space(3))) unsigned int*)l,
        16, 0, 0);
}

// ------------- fused fp32->bf16: K row-major, V transposed vt[bh][d][s] -------------
__global__ __launch_bounds__(256) void cvt_kv(
    const float* __restrict__ k, const float* __restrict__ v,
    unsigned short* __restrict__ kb, unsigned short* __restrict__ vt) {
    __shared__ unsigned short T[DIM][72];   // 64 s-rows transposed; 144B row stride
    const int bh = blockIdx.y;
    const int s0 = blockIdx.x * 64;
    const int t  = threadIdx.x;
    const long rbase = ((long)bh * SEQ + s0) * DIM;

    // K: 64 rows x 128 = 8192 elems, 32/thread
    #pragma unroll
    for (int u = 0; u < 2; ++u) {
        long e = rbase + (long)(t + u * 256) * 16;
        const float* src = k + e;
        unsigned short* dst = kb + e;
        #pragma unroll
        for (int h = 0; h < 2; ++h) {
            float4 a0 = *(const float4*)(src + h * 8);
            float4 a1 = *(const float4*)(src + h * 8 + 4);
            union { uint4 u4; unsigned short s[8]; } p;
            p.s[0]=f2bf(a0.x); p.s[1]=f2bf(a0.y); p.s[2]=f2bf(a0.z); p.s[3]=f2bf(a0.w);
            p.s[4]=f2bf(a1.x); p.s[5]=f2bf(a1.y); p.s[6]=f2bf(a1.z); p.s[7]=f2bf(a1.w);
            *(uint4*)(dst + h * 8) = p.u4;
        }
    }
    // V: stage transposed through LDS
    {
        const int r = t >> 2, i = t & 3;
        const float* src = v + rbase + (long)r * DIM + i * 32;
        #pragma unroll
        for (int j = 0; j < 8; ++j) {
            float4 x = *(const float4*)(src + j * 4);
            const int d = i * 32 + j * 4;
            T[d + 0][r] = f2bf(x.x); T[d + 1][r] = f2bf(x.y);
            T[d + 2][r] = f2bf(x.z); T[d + 3][r] = f2bf(x.w);
        }
    }
    __syncthreads();
    {
        const int d = t >> 1, h = t & 1;
        unsigned short* dst = vt + ((long)bh * DIM + d) * SEQ + s0 + h * 32;
        #pragma unroll
        for (int m = 0; m < 4; ++m)
            *(uint4*)(dst + m * 8) = *(const uint4*)&T[d][h * 32 + m * 8];
    }
}

// ---------------- flash attention ----------------
// __launch_bounds__(256, 4): LDS 37.9KB*4 = 151.5KB <= 160KB, VGPR cap 128 (was 100).
// 4 blocks/CU * 256 CUs = 1024 = whole grid co-resident.
__global__ __launch_bounds__(256, 4) void attn_fwd(
    const float* __restrict__ qg,
    const unsigned short* __restrict__ kb,
    const unsigned short* __restrict__ vtg,
    float* __restrict__ out) {

    // Unpadded (global_load_lds-compatible); XOR chunk swizzle kills bank conflicts.
    __shared__ unsigned short Kt[2][KT][DIM];    // 2 x 32 x 128 (8 KB each)
    __shared__ unsigned short Vt[2][DIM][KT];    // 2 x 128 x 32 (8 KB each)
    __shared__ unsigned short Pl[4][16][KT + 8]; // per-wave P tile [q][k], padded (ds_write path)

    const int tid  = threadIdx.x;
    const int w    = tid >> 6;
    const int lane = tid & 63;
    const int quad = lane >> 4;
    const int ql   = lane & 15;

    // Work-balance + locality swizzle (1-D grid, 1024 blocks):
    //   xcd  = flat & 7      -> round-robin XCD dispatch assumption (speed-only heuristic)
    //   bh   = xcd*8 + slot%8 -> each XCD sees a contiguous 8-bh range; a CU's
    //                            co-resident blocks (slot spaced 32) share bh (L2 reuse)
    //   xb   = slot/8        -> co-resident blocks get xb spaced 4 apart: causal work
    //                            per CU balanced (112..160 tile-iters vs 16..256 before)
    const int flat = blockIdx.x;
    const int xcd  = flat & 7;
    const int slot = flat >> 3;
    const int bh   = (xcd << 3) | (slot & 7);
    const int xb   = (NXB - 1) - (slot >> 3);      // heavy (diagonal) blocks dispatched first
    const int qb0 = xb * BQ;
    const int qw0 = qb0 + w * WQ;

    const long base = (long)bh * SEQ * DIM;
    const float scale = 0.08838834764831845f;      // 1/sqrt(128), folded into Q

    // ---- Q fragments (B-operand for Sc = K*Q^T), pre-scaled ----
    bf16x8 qf[2][4];
    #pragma unroll
    for (int mb = 0; mb < 2; ++mb) {
        const float* qr = qg + base + (long)(qw0 + mb * 16 + ql) * DIM;
        #pragma unroll
        for (int c = 0; c < 4; ++c) {
            const float* p = qr + c * 32 + quad * 8;
            float4 x = *(const float4*)(p);
            float4 y = *(const float4*)(p + 4);
            union { bf16x8 v; unsigned short s[8]; } u;
            u.s[0]=f2bf(x.x*scale); u.s[1]=f2bf(x.y*scale);
            u.s[2]=f2bf(x.z*scale); u.s[3]=f2bf(x.w*scale);
            u.s[4]=f2bf(y.x*scale); u.s[5]=f2bf(y.y*scale);
            u.s[6]=f2bf(y.z*scale); u.s[7]=f2bf(y.w*scale);
            qf[mb][c] = u.v;
        }
    }

    f32x4 acc[2][8];
    #pragma unroll
    for (int mb = 0; mb < 2; ++mb)
        #pragma unroll
        for (int n = 0; n < 8; ++n)
            acc[mb][n] = (f32x4){0.f, 0.f, 0.f, 0.f};

    float m_[2] = {-INFINITY, -INFINITY};
    float l_[2] = {0.f, 0.f};

    // async stage of one 32-k tile into buffer `buf` (4 DMA/thread, 0 data VGPRs)
    auto stage = [&](int buf, int k0) {
        #pragma unroll
        for (int i = 0; i < 2; ++i) {
            const int idx = tid + i * 256;          // chunk id, 512 x 16B per tensor
            // K: row r, lds chunk (idx&15) holds global chunk (idx&15)^(r&15)
            const int r   = idx >> 4;
            const int chg = (idx & 15) ^ (r & 15);
            async_cp16(kb + base + (long)(k0 + r) * DIM + chg * 8,
                       &Kt[buf][0][0] + ((tid >> 6) * 64 + i * 256) * 8);
            // V: row d, lds chunk (idx&3) holds global chunk (idx&3)^((d>>1)&3)
            const int d   = idx >> 2;
            const int cvg = (idx & 3) ^ ((d >> 1) & 3);
            async_cp16(vtg + base + (long)d * SEQ + k0 + cvg * 8,
                       &Vt[buf][0][0] + ((tid >> 6) * 64 + i * 256) * 8);
        }
    };

    const int ntile = (qb0 + BQ) / KT;

    stage(0, 0);

    for (int t = 0; t < ntile; ++t) {
        const int buf = t & 1;
        const int k0  = t * KT;
        __syncthreads();   // vmcnt(0) drain: tile t resident; prev readers of other buf done

        if (t + 1 < ntile) stage(buf ^ 1, k0 + KT);   // in flight during compute of tile t

        const bool active = (k0 < qw0 + WQ);
        if (active) {
            // ---- Sc = K * Q^T  (rows=k, cols=q) ----
            f32x4 sacc[2][2];
            #pragma unroll
            for (int mb = 0; mb < 2; ++mb)
                #pragma unroll
                for (int kk = 0; kk < 2; ++kk)
                    sacc[mb][kk] = (f32x4){0.f, 0.f, 0.f, 0.f};
            #pragma unroll
            for (int c = 0; c < 4; ++c) {
                const int sw = ((c * 4 + quad) ^ ql) * 8;   // swizzled chunk offset
                bf16x8 kf0 = *(const bf16x8*)&Kt[buf][ql]     [sw];
                bf16x8 kf1 = *(const bf16x8*)&Kt[buf][16 + ql][sw];
                #pragma unroll
                for (int mb = 0; mb < 2; ++mb) {
                    sacc[mb][0] = __builtin_amdgcn_mfma_f32_16x16x32_bf16(kf0, qf[mb][c], sacc[mb][0], 0, 0, 0);
                    sacc[mb][1] = __builtin_amdgcn_mfma_f32_16x16x32_bf16(kf1, qf[mb][c], sacc[mb][1], 0, 0, 0);
                }
            }

            // V fragments (swizzled)
            bf16x8 vf[8];
            #pragma unroll
            for (int n = 0; n < 8; ++n)
                vf[n] = *(const bf16x8*)&Vt[buf][n * 16 + ql][(quad ^ ((ql >> 1) & 3)) * 8];

            #pragma unroll
            for (int mb = 0; mb < 2; ++mb) {
                const int qrow   = qw0 + mb * 16 + ql;
                const bool needm = (k0 + KT - 1 > qw0 + mb * 16);  // wave-uniform
                float s[2][4];
                float tmax = -INFINITY;
                #pragma unroll
                for (int kk = 0; kk < 2; ++kk)
                    #pragma unroll
                    for (int r = 0; r < 4; ++r) {
                        float sv = sacc[mb][kk][r];
                        if (needm) {
                            int kg = k0 + kk * 16 + quad * 4 + r;
                            sv = (kg <= qrow) ? sv : -INFINITY;
                        }
                        s[kk][r] = sv;
                        tmax = fmaxf(tmax, sv);
                    }
                tmax = fmaxf(tmax, __shfl_xor(tmax, 16));
                tmax = fmaxf(tmax, __shfl_xor(tmax, 32));
                float mnew  = fmaxf(m_[mb], tmax);
                float alpha = __expf(m_[mb] - mnew);
                float rsum = 0.f;
                #pragma unroll
                for (int kk = 0; kk < 2; ++kk)
                    #pragma unroll
                    for (int r = 0; r < 4; ++r) {
                        float p = __expf(s[kk][r] - mnew);
                        s[kk][r] = p;
                        rsum += p;
                    }
                rsum += __shfl_xor(rsum, 16);
                rsum += __shfl_xor(rsum, 32);
                l_[mb] = l_[mb] * alpha + rsum;
                m_[mb] = mnew;

                // P -> per-wave LDS (same-wave DS ordering; no barrier)
                #pragma unroll
                for (int kk = 0; kk < 2; ++kk) {
                    union { uint2 u; unsigned short h[4]; } pu;
                    #pragma unroll
                    for (int r = 0; r < 4; ++r) pu.h[r] = f2bf(s[kk][r]);
                    *(uint2*)&Pl[w][ql][kk * 16 + quad * 4] = pu.u;
                }

                // rescale O rows (row q = quad*4+r in C-layout)
                #pragma unroll
                for (int r = 0; r < 4; ++r) {
                    float ar = __shfl(alpha, quad * 4 + r);
                    #pragma unroll
                    for (int n = 0; n < 8; ++n) acc[mb][n][r] *= ar;
                }

                bf16x8 pf = *(const bf16x8*)&Pl[w][ql][quad * 8];
                #pragma unroll
                for (int n = 0; n < 8; ++n)
                    acc[mb][n] = __builtin_amdgcn_mfma_f32_16x16x32_bf16(pf, vf[n], acc[mb][n], 0, 0, 0);
            }
        }
    }

    // ---- epilogue: O / l ----
    #pragma unroll
    for (int mb = 0; mb < 2; ++mb) {
        #pragma unroll
        for (int r = 0; r < 4; ++r) {
            float lr = __shfl(l_[mb], quad * 4 + r);
            float il = 1.0f / lr;
            long orow = base + (long)(qw0 + mb * 16 + quad * 4 + r) * DIM;
            #pragma unroll
            for (int n = 0; n < 8; ++n)
                out[orow + n * 16 + ql] = acc[mb][n][r] * il;
        }
    }
}

extern "C" void kernel_launch(void* const* d_in, const int* in_sizes, int n_in,
                              void* d_out, int out_size, void* d_ws, size_t ws_size,
                              hipStream_t stream) {
    const float* k = (const float*)d_in[0];
    const float* q = (const float*)d_in[1];
    const float* v = (const float*)d_in[2];
    float* o = (float*)d_out;

    unsigned short* kb = (unsigned short*)d_ws;
    unsigned short* vt = kb + (size_t)BHN * SEQ * DIM;

    cvt_kv<<<dim3(SEQ / 64, BHN), dim3(256), 0, stream>>>(k, v, kb, vt);

    attn_fwd<<<dim3(NXB * BHN), dim3(256), 0, stream>>>(q, kb, vt, o);
}

// Round 2
// 357.803 us; speedup vs baseline: 2.2058x; 2.2058x over previous
//
#include <hip/hip_runtime.h>
#include <hip/hip_bf16.h>
#include <math.h>

#define BATCH 4
#define HEADS 16
#define SEQ   2048
#define DIM   128
#define BHN   (BATCH*HEADS)

#define BQ 128   // q rows per block
#define WQ 32    // q rows per wave (2 MFMA M-blocks)
#define KT 32    // k rows per stage/compute tile
#define NXB (SEQ/BQ)   // 16 q-blocks per bh

typedef short bf16x8 __attribute__((ext_vector_type(8)));
typedef float f32x4  __attribute__((ext_vector_type(4)));

static __device__ __forceinline__ unsigned short f2bf(float f) {
    union { float f; unsigned u; } x; x.f = f;
    unsigned r = x.u + 0x7FFF + ((x.u >> 16) & 1);  // RNE
    return (unsigned short)(r >> 16);
}

// async 16B global -> LDS (no data VGPRs; LDS dest = wave-uniform base + lane*16)
static __device__ __forceinline__ void async_cp16(const unsigned short* g, unsigned short* l) {
    __builtin_amdgcn_global_load_lds(
        (const __attribute__((address_space(1))) unsigned int*)g,
        (__attribute__((address_space(3))) unsigned int*)l,
        16, 0, 0);
}

// ------------- fused fp32->bf16: K row-major, V transposed vt[bh][d][s] -------------
__global__ __launch_bounds__(256) void cvt_kv(
    const float* __restrict__ k, const float* __restrict__ v,
    unsigned short* __restrict__ kb, unsigned short* __restrict__ vt) {
    __shared__ unsigned short T[DIM][72];   // 64 s-rows transposed; 144B row stride
    const int bh = blockIdx.y;
    const int s0 = blockIdx.x * 64;
    const int t  = threadIdx.x;
    const long rbase = ((long)bh * SEQ + s0) * DIM;

    // K: 64 rows x 128 = 8192 elems, 32/thread
    #pragma unroll
    for (int u = 0; u < 2; ++u) {
        long e = rbase + (long)(t + u * 256) * 16;
        const float* src = k + e;
        unsigned short* dst = kb + e;
        #pragma unroll
        for (int h = 0; h < 2; ++h) {
            float4 a0 = *(const float4*)(src + h * 8);
            float4 a1 = *(const float4*)(src + h * 8 + 4);
            union { uint4 u4; unsigned short s[8]; } p;
            p.s[0]=f2bf(a0.x); p.s[1]=f2bf(a0.y); p.s[2]=f2bf(a0.z); p.s[3]=f2bf(a0.w);
            p.s[4]=f2bf(a1.x); p.s[5]=f2bf(a1.y); p.s[6]=f2bf(a1.z); p.s[7]=f2bf(a1.w);
            *(uint4*)(dst + h * 8) = p.u4;
        }
    }
    // V: stage transposed through LDS
    {
        const int r = t >> 2, i = t & 3;
        const float* src = v + rbase + (long)r * DIM + i * 32;
        #pragma unroll
        for (int j = 0; j < 8; ++j) {
            float4 x = *(const float4*)(src + j * 4);
            const int d = i * 32 + j * 4;
            T[d + 0][r] = f2bf(x.x); T[d + 1][r] = f2bf(x.y);
            T[d + 2][r] = f2bf(x.z); T[d + 3][r] = f2bf(x.w);
        }
    }
    __syncthreads();
    {
        const int d = t >> 1, h = t & 1;
        unsigned short* dst = vt + ((long)bh * DIM + d) * SEQ + s0 + h * 32;
        #pragma unroll
        for (int m = 0; m < 4; ++m)
            *(uint4*)(dst + m * 8) = *(const uint4*)&T[d][h * 32 + m * 8];
    }
}

// ---------------- flash attention ----------------
// __launch_bounds__(256, 2): combined VGPR+AGPR footprint ~164 regs -> HW runs
// 3 waves/SIMD (512/164) = 3 blocks/CU naturally. (256,4) forced a 128-reg cap
// and spilled ~1.6 GB/dispatch to scratch (R1 post-mortem) — do not raise it.
__global__ __launch_bounds__(256, 2) void attn_fwd(
    const float* __restrict__ qg,
    const unsigned short* __restrict__ kb,
    const unsigned short* __restrict__ vtg,
    float* __restrict__ out) {

    // Unpadded (global_load_lds-compatible); XOR chunk swizzle kills bank conflicts.
    __shared__ unsigned short Kt[2][KT][DIM];    // 2 x 32 x 128 (8 KB each)
    __shared__ unsigned short Vt[2][DIM][KT];    // 2 x 128 x 32 (8 KB each)
    __shared__ unsigned short Pl[4][16][KT + 8]; // per-wave P tile [q][k], padded (ds_write path)

    const int tid  = threadIdx.x;
    const int w    = tid >> 6;
    const int lane = tid & 63;
    const int quad = lane >> 4;
    const int ql   = lane & 15;

    // Work-balance + locality swizzle (1-D grid, 1024 blocks):
    //   xcd = flat & 7        -> round-robin XCD dispatch heuristic (speed-only)
    //   bh  = xcd*8 + slot%8  -> each XCD owns a contiguous 8-bh range; a CU's
    //                            co-resident blocks (flat spaced 256 -> slot spaced 32)
    //                            share bh => K/V L2 reuse
    //   xb  = xbmap[slot/8]   -> co-resident blocks have slot/8 spaced 4; map each
    //                            residue class {i,i+4,i+8,i+12} to xb sets summing to
    //                            30 => every CU executes exactly 136 tile-iters
    //                            (was 64..256, a 16x causal-work spread).
    //                            Heavy diagonal blocks (xb=15,14,..) dispatch first.
    const int flat = blockIdx.x;
    const int xcd  = flat & 7;
    const int slot = flat >> 3;
    const int bh   = (xcd << 3) | (slot & 7);
    const int shi  = slot >> 3;
    // xbmap = {15,14,13,12, 0,1,2,3, 8,9,10,11, 7,6,5,4}
    const int xb   = (shi < 4) ? (15 - shi)
                   : (shi < 8) ? (shi - 4)
                   : (shi < 12) ? shi
                   : (19 - shi);
    const int qb0 = xb * BQ;
    const int qw0 = qb0 + w * WQ;

    const long base = (long)bh * SEQ * DIM;
    const float scale = 0.08838834764831845f;      // 1/sqrt(128), folded into Q

    // ---- Q fragments (B-operand for Sc = K*Q^T), pre-scaled ----
    bf16x8 qf[2][4];
    #pragma unroll
    for (int mb = 0; mb < 2; ++mb) {
        const float* qr = qg + base + (long)(qw0 + mb * 16 + ql) * DIM;
        #pragma unroll
        for (int c = 0; c < 4; ++c) {
            const float* p = qr + c * 32 + quad * 8;
            float4 x = *(const float4*)(p);
            float4 y = *(const float4*)(p + 4);
            union { bf16x8 v; unsigned short s[8]; } u;
            u.s[0]=f2bf(x.x*scale); u.s[1]=f2bf(x.y*scale);
            u.s[2]=f2bf(x.z*scale); u.s[3]=f2bf(x.w*scale);
            u.s[4]=f2bf(y.x*scale); u.s[5]=f2bf(y.y*scale);
            u.s[6]=f2bf(y.z*scale); u.s[7]=f2bf(y.w*scale);
            qf[mb][c] = u.v;
        }
    }

    f32x4 acc[2][8];
    #pragma unroll
    for (int mb = 0; mb < 2; ++mb)
        #pragma unroll
        for (int n = 0; n < 8; ++n)
            acc[mb][n] = (f32x4){0.f, 0.f, 0.f, 0.f};

    float m_[2] = {-INFINITY, -INFINITY};
    float l_[2] = {0.f, 0.f};

    // async stage of one 32-k tile into buffer `buf` (4 DMA/thread, 0 data VGPRs)
    auto stage = [&](int buf, int k0) {
        #pragma unroll
        for (int i = 0; i < 2; ++i) {
            const int idx = tid + i * 256;          // chunk id, 512 x 16B per tensor
            // K: row r, lds chunk (idx&15) holds global chunk (idx&15)^(r&15)
            const int r   = idx >> 4;
            const int chg = (idx & 15) ^ (r & 15);
            async_cp16(kb + base + (long)(k0 + r) * DIM + chg * 8,
                       &Kt[buf][0][0] + ((tid >> 6) * 64 + i * 256) * 8);
            // V: row d, lds chunk (idx&3) holds global chunk (idx&3)^((d>>1)&3)
            const int d   = idx >> 2;
            const int cvg = (idx & 3) ^ ((d >> 1) & 3);
            async_cp16(vtg + base + (long)d * SEQ + k0 + cvg * 8,
                       &Vt[buf][0][0] + ((tid >> 6) * 64 + i * 256) * 8);
        }
    };

    const int ntile = (qb0 + BQ) / KT;

    stage(0, 0);

    for (int t = 0; t < ntile; ++t) {
        const int buf = t & 1;
        const int k0  = t * KT;
        __syncthreads();   // vmcnt(0) drain: tile t resident; prev readers of other buf done

        if (t + 1 < ntile) stage(buf ^ 1, k0 + KT);   // in flight during compute of tile t

        const bool active = (k0 < qw0 + WQ);
        if (active) {
            // ---- Sc = K * Q^T  (rows=k, cols=q) ----
            f32x4 sacc[2][2];
            #pragma unroll
            for (int mb = 0; mb < 2; ++mb)
                #pragma unroll
                for (int kk = 0; kk < 2; ++kk)
                    sacc[mb][kk] = (f32x4){0.f, 0.f, 0.f, 0.f};
            #pragma unroll
            for (int c = 0; c < 4; ++c) {
                const int sw = ((c * 4 + quad) ^ ql) * 8;   // swizzled chunk offset
                bf16x8 kf0 = *(const bf16x8*)&Kt[buf][ql]     [sw];
                bf16x8 kf1 = *(const bf16x8*)&Kt[buf][16 + ql][sw];
                #pragma unroll
                for (int mb = 0; mb < 2; ++mb) {
                    sacc[mb][0] = __builtin_amdgcn_mfma_f32_16x16x32_bf16(kf0, qf[mb][c], sacc[mb][0], 0, 0, 0);
                    sacc[mb][1] = __builtin_amdgcn_mfma_f32_16x16x32_bf16(kf1, qf[mb][c], sacc[mb][1], 0, 0, 0);
                }
            }

            // V fragments (swizzled)
            bf16x8 vf[8];
            #pragma unroll
            for (int n = 0; n < 8; ++n)
                vf[n] = *(const bf16x8*)&Vt[buf][n * 16 + ql][(quad ^ ((ql >> 1) & 3)) * 8];

            #pragma unroll
            for (int mb = 0; mb < 2; ++mb) {
                const int qrow   = qw0 + mb * 16 + ql;
                const bool needm = (k0 + KT - 1 > qw0 + mb * 16);  // wave-uniform
                float s[2][4];
                float tmax = -INFINITY;
                #pragma unroll
                for (int kk = 0; kk < 2; ++kk)
                    #pragma unroll
                    for (int r = 0; r < 4; ++r) {
                        float sv = sacc[mb][kk][r];
                        if (needm) {
                            int kg = k0 + kk * 16 + quad * 4 + r;
                            sv = (kg <= qrow) ? sv : -INFINITY;
                        }
                        s[kk][r] = sv;
                        tmax = fmaxf(tmax, sv);
                    }
                tmax = fmaxf(tmax, __shfl_xor(tmax, 16));
                tmax = fmaxf(tmax, __shfl_xor(tmax, 32));
                float mnew  = fmaxf(m_[mb], tmax);
                float alpha = __expf(m_[mb] - mnew);
                float rsum = 0.f;
                #pragma unroll
                for (int kk = 0; kk < 2; ++kk)
                    #pragma unroll
                    for (int r = 0; r < 4; ++r) {
                        float p = __expf(s[kk][r] - mnew);
                        s[kk][r] = p;
                        rsum += p;
                    }
                rsum += __shfl_xor(rsum, 16);
                rsum += __shfl_xor(rsum, 32);
                l_[mb] = l_[mb] * alpha + rsum;
                m_[mb] = mnew;

                // P -> per-wave LDS (same-wave DS ordering; no barrier)
                #pragma unroll
                for (int kk = 0; kk < 2; ++kk) {
                    union { uint2 u; unsigned short h[4]; } pu;
                    #pragma unroll
                    for (int r = 0; r < 4; ++r) pu.h[r] = f2bf(s[kk][r]);
                    *(uint2*)&Pl[w][ql][kk * 16 + quad * 4] = pu.u;
                }

                // rescale O rows (row q = quad*4+r in C-layout)
                #pragma unroll
                for (int r = 0; r < 4; ++r) {
                    float ar = __shfl(alpha, quad * 4 + r);
                    #pragma unroll
                    for (int n = 0; n < 8; ++n) acc[mb][n][r] *= ar;
                }

                bf16x8 pf = *(const bf16x8*)&Pl[w][ql][quad * 8];
                #pragma unroll
                for (int n = 0; n < 8; ++n)
                    acc[mb][n] = __builtin_amdgcn_mfma_f32_16x16x32_bf16(pf, vf[n], acc[mb][n], 0, 0, 0);
            }
        }
    }

    // ---- epilogue: O / l ----
    #pragma unroll
    for (int mb = 0; mb < 2; ++mb) {
        #pragma unroll
        for (int r = 0; r < 4; ++r) {
            float lr = __shfl(l_[mb], quad * 4 + r);
            float il = 1.0f / lr;
            long orow = base + (long)(qw0 + mb * 16 + quad * 4 + r) * DIM;
            #pragma unroll
            for (int n = 0; n < 8; ++n)
                out[orow + n * 16 + ql] = acc[mb][n][r] * il;
        }
    }
}

extern "C" void kernel_launch(void* const* d_in, const int* in_sizes, int n_in,
                              void* d_out, int out_size, void* d_ws, size_t ws_size,
                              hipStream_t stream) {
    const float* k = (const float*)d_in[0];
    const float* q = (const float*)d_in[1];
    const float* v = (const float*)d_in[2];
    float* o = (float*)d_out;

    unsigned short* kb = (unsigned short*)d_ws;
    unsigned short* vt = kb + (size_t)BHN * SEQ * DIM;

    cvt_kv<<<dim3(SEQ / 64, BHN), dim3(256), 0, stream>>>(k, v, kb, vt);

    attn_fwd<<<dim3(NXB * BHN), dim3(256), 0, stream>>>(q, kb, vt, o);
}

// Round 3
// 352.408 us; speedup vs baseline: 2.2395x; 1.0153x over previous
//
#include <hip/hip_runtime.h>
#include <hip/hip_bf16.h>
#include <math.h>

#define BATCH 4
#define HEADS 16
#define SEQ   2048
#define DIM   128
#define BHN   (BATCH*HEADS)

#define BQ 128   // q rows per block
#define WQ 32    // q rows per wave (2 MFMA M-blocks)
#define KT 32    // k rows per stage/compute tile
#define NXB (SEQ/BQ)   // 16 q-blocks per bh

typedef short bf16x8 __attribute__((ext_vector_type(8)));
typedef float f32x4  __attribute__((ext_vector_type(4)));

static __device__ __forceinline__ unsigned short f2bf(float f) {
    union { float f; unsigned u; } x; x.f = f;
    unsigned r = x.u + 0x7FFF + ((x.u >> 16) & 1);  // RNE
    return (unsigned short)(r >> 16);
}

// async 16B global -> LDS (no data VGPRs; LDS dest = wave-uniform base + lane*16)
static __device__ __forceinline__ void async_cp16(const unsigned short* g, unsigned short* l) {
    __builtin_amdgcn_global_load_lds(
        (const __attribute__((address_space(1))) unsigned int*)g,
        (__attribute__((address_space(3))) unsigned int*)l,
        16, 0, 0);
}

// ------------- fused fp32->bf16: K row-major, V transposed vt[bh][d][s] -------------
__global__ __launch_bounds__(256) void cvt_kv(
    const float* __restrict__ k, const float* __restrict__ v,
    unsigned short* __restrict__ kb, unsigned short* __restrict__ vt) {
    __shared__ unsigned short T[DIM][72];   // 64 s-rows transposed; 144B row stride
    const int bh = blockIdx.y;
    const int s0 = blockIdx.x * 64;
    const int t  = threadIdx.x;
    const long rbase = ((long)bh * SEQ + s0) * DIM;

    // K: 64 rows x 128 = 8192 elems, 32/thread
    #pragma unroll
    for (int u = 0; u < 2; ++u) {
        long e = rbase + (long)(t + u * 256) * 16;
        const float* src = k + e;
        unsigned short* dst = kb + e;
        #pragma unroll
        for (int h = 0; h < 2; ++h) {
            float4 a0 = *(const float4*)(src + h * 8);
            float4 a1 = *(const float4*)(src + h * 8 + 4);
            union { uint4 u4; unsigned short s[8]; } p;
            p.s[0]=f2bf(a0.x); p.s[1]=f2bf(a0.y); p.s[2]=f2bf(a0.z); p.s[3]=f2bf(a0.w);
            p.s[4]=f2bf(a1.x); p.s[5]=f2bf(a1.y); p.s[6]=f2bf(a1.z); p.s[7]=f2bf(a1.w);
            *(uint4*)(dst + h * 8) = p.u4;
        }
    }
    // V: stage transposed through LDS
    {
        const int r = t >> 2, i = t & 3;
        const float* src = v + rbase + (long)r * DIM + i * 32;
        #pragma unroll
        for (int j = 0; j < 8; ++j) {
            float4 x = *(const float4*)(src + j * 4);
            const int d = i * 32 + j * 4;
            T[d + 0][r] = f2bf(x.x); T[d + 1][r] = f2bf(x.y);
            T[d + 2][r] = f2bf(x.z); T[d + 3][r] = f2bf(x.w);
        }
    }
    __syncthreads();
    {
        const int d = t >> 1, h = t & 1;
        unsigned short* dst = vt + ((long)bh * DIM + d) * SEQ + s0 + h * 32;
        #pragma unroll
        for (int m = 0; m < 4; ++m)
            *(uint4*)(dst + m * 8) = *(const uint4*)&T[d][h * 32 + m * 8];
    }
}

// ---------------- flash attention ----------------
// __launch_bounds__(256, 2): combined VGPR+AGPR footprint ~165 regs -> 3 waves/SIMD HW.
// (256,4) forced a 128-reg cap and spilled ~1.6 GB/dispatch (R1). Do not raise past
// what the register footprint allows; check WRITE_SIZE for spill on any change.
__global__ __launch_bounds__(256, 2) void attn_fwd(
    const float* __restrict__ qg,
    const unsigned short* __restrict__ kb,
    const unsigned short* __restrict__ vtg,
    float* __restrict__ out) {

    // Unpadded (global_load_lds-compatible); XOR chunk swizzle kills bank conflicts.
    __shared__ unsigned short Kt[2][KT][DIM];       // 2 x 32 x 128 (8 KB each)
    __shared__ unsigned short Vt[2][DIM][KT];       // 2 x 128 x 32 (8 KB each)
    __shared__ unsigned short Pl[4][2][16][KT + 8]; // per-wave, per-mb P tile [q][k]
                                                    // (2 buffers: write both, then read both,
                                                    //  so mb=1 softmax hides mb=0's ds lgkm)

    const int tid  = threadIdx.x;
    const int w    = tid >> 6;
    const int lane = tid & 63;
    const int quad = lane >> 4;
    const int ql   = lane & 15;

    // Work-balance + locality swizzle (1-D grid, 1024 blocks) — R2-verified:
    //   occupancy 11.7->18.4%, FETCH 241->108MB, attn 275->175us.
    const int flat = blockIdx.x;
    const int xcd  = flat & 7;
    const int slot = flat >> 3;
    const int bh   = (xcd << 3) | (slot & 7);
    const int shi  = slot >> 3;
    // xbmap = {15,14,13,12, 0,1,2,3, 8,9,10,11, 7,6,5,4}: residue classes sum to 30
    const int xb   = (shi < 4) ? (15 - shi)
                   : (shi < 8) ? (shi - 4)
                   : (shi < 12) ? shi
                   : (19 - shi);
    const int qb0 = xb * BQ;
    const int qw0 = qb0 + w * WQ;

    const long base = (long)bh * SEQ * DIM;
    // exp2 domain: fold log2(e) into the Q scale so p = exp2(s' - m') with a bare
    // v_exp_f32 (saves the hidden mul in __expf for every score element).
    const float scale = 0.08838834764831845f * 1.4426950408889634f;

    // ---- Q fragments (B-operand for Sc = K*Q^T), pre-scaled ----
    bf16x8 qf[2][4];
    #pragma unroll
    for (int mb = 0; mb < 2; ++mb) {
        const float* qr = qg + base + (long)(qw0 + mb * 16 + ql) * DIM;
        #pragma unroll
        for (int c = 0; c < 4; ++c) {
            const float* p = qr + c * 32 + quad * 8;
            float4 x = *(const float4*)(p);
            float4 y = *(const float4*)(p + 4);
            union { bf16x8 v; unsigned short s[8]; } u;
            u.s[0]=f2bf(x.x*scale); u.s[1]=f2bf(x.y*scale);
            u.s[2]=f2bf(x.z*scale); u.s[3]=f2bf(x.w*scale);
            u.s[4]=f2bf(y.x*scale); u.s[5]=f2bf(y.y*scale);
            u.s[6]=f2bf(y.z*scale); u.s[7]=f2bf(y.w*scale);
            qf[mb][c] = u.v;
        }
    }

    f32x4 acc[2][8];
    #pragma unroll
    for (int mb = 0; mb < 2; ++mb)
        #pragma unroll
        for (int n = 0; n < 8; ++n)
            acc[mb][n] = (f32x4){0.f, 0.f, 0.f, 0.f};

    float m_[2] = {-INFINITY, -INFINITY};
    float l_[2] = {0.f, 0.f};

    // async stage of one 32-k tile into buffer `buf` (4 DMA/thread, 0 data VGPRs)
    auto stage = [&](int buf, int k0) {
        #pragma unroll
        for (int i = 0; i < 2; ++i) {
            const int idx = tid + i * 256;          // chunk id, 512 x 16B per tensor
            // K: row r, lds chunk (idx&15) holds global chunk (idx&15)^(r&15)
            const int r   = idx >> 4;
            const int chg = (idx & 15) ^ (r & 15);
            async_cp16(kb + base + (long)(k0 + r) * DIM + chg * 8,
                       &Kt[buf][0][0] + ((tid >> 6) * 64 + i * 256) * 8);
            // V: row d, lds chunk (idx&3) holds global chunk (idx&3)^((d>>1)&3)
            const int d   = idx >> 2;
            const int cvg = (idx & 3) ^ ((d >> 1) & 3);
            async_cp16(vtg + base + (long)d * SEQ + k0 + cvg * 8,
                       &Vt[buf][0][0] + ((tid >> 6) * 64 + i * 256) * 8);
        }
    };

    const int ntile = (qb0 + BQ) / KT;

    stage(0, 0);

    for (int t = 0; t < ntile; ++t) {
        const int buf = t & 1;
        const int k0  = t * KT;
        __syncthreads();   // vmcnt(0) drain: tile t resident; prev readers of other buf done

        if (t + 1 < ntile) stage(buf ^ 1, k0 + KT);   // in flight during compute of tile t

        const bool active = (k0 < qw0 + WQ);
        if (active) {
            // ---- Sc = K * Q^T  (rows=k, cols=q) ----
            f32x4 sacc[2][2];
            #pragma unroll
            for (int mb = 0; mb < 2; ++mb)
                #pragma unroll
                for (int kk = 0; kk < 2; ++kk)
                    sacc[mb][kk] = (f32x4){0.f, 0.f, 0.f, 0.f};
            #pragma unroll
            for (int c = 0; c < 4; ++c) {
                const int sw = ((c * 4 + quad) ^ ql) * 8;   // swizzled chunk offset
                bf16x8 kf0 = *(const bf16x8*)&Kt[buf][ql]     [sw];
                bf16x8 kf1 = *(const bf16x8*)&Kt[buf][16 + ql][sw];
                #pragma unroll
                for (int mb = 0; mb < 2; ++mb) {
                    sacc[mb][0] = __builtin_amdgcn_mfma_f32_16x16x32_bf16(kf0, qf[mb][c], sacc[mb][0], 0, 0, 0);
                    sacc[mb][1] = __builtin_amdgcn_mfma_f32_16x16x32_bf16(kf1, qf[mb][c], sacc[mb][1], 0, 0, 0);
                }
            }

            // V fragments (swizzled)
            bf16x8 vf[8];
            #pragma unroll
            for (int n = 0; n < 8; ++n)
                vf[n] = *(const bf16x8*)&Vt[buf][n * 16 + ql][(quad ^ ((ql >> 1) & 3)) * 8];

            // ---- softmax both mb, write both P tiles (defer-max, exp2 domain) ----
            float alpha_[2];
            bool  resc_[2];
            #pragma unroll
            for (int mb = 0; mb < 2; ++mb) {
                const int qrow   = qw0 + mb * 16 + ql;
                const bool needm = (k0 + KT - 1 > qw0 + mb * 16);  // wave-uniform
                float s[2][4];
                float tmax = -INFINITY;
                #pragma unroll
                for (int kk = 0; kk < 2; ++kk)
                    #pragma unroll
                    for (int r = 0; r < 4; ++r) {
                        float sv = sacc[mb][kk][r];
                        if (needm) {
                            int kg = k0 + kk * 16 + quad * 4 + r;
                            sv = (kg <= qrow) ? sv : -INFINITY;
                        }
                        s[kk][r] = sv;
                        tmax = fmaxf(tmax, sv);
                    }
                tmax = fmaxf(tmax, __shfl_xor(tmax, 16));
                tmax = fmaxf(tmax, __shfl_xor(tmax, 32));

                // T13 defer-max: skip O-rescale while tile max stays within 8 (log2
                // units) of the running max; P bounded by 2^8=256 (bf16/f32-safe).
                // First tile: m_=-inf -> full path (alpha=exp2(-inf)=0, acc is 0).
                const bool skip = __all(tmax <= m_[mb] + 8.0f);
                const float mnew = skip ? m_[mb] : fmaxf(m_[mb], tmax);

                float rsum = 0.f;
                #pragma unroll
                for (int kk = 0; kk < 2; ++kk) {
                    float p0 = __builtin_amdgcn_exp2f(s[kk][0] - mnew);
                    float p1 = __builtin_amdgcn_exp2f(s[kk][1] - mnew);
                    float p2 = __builtin_amdgcn_exp2f(s[kk][2] - mnew);
                    float p3 = __builtin_amdgcn_exp2f(s[kk][3] - mnew);
                    rsum += (p0 + p1) + (p2 + p3);
                    // packed RNE convert: v_cvt_pk_bf16_f32 (was 4x manual bit-math)
                    union { uint2 u; __hip_bfloat162 h[2]; } pu;
                    pu.h[0] = __float22bfloat162_rn(float2{p0, p1});
                    pu.h[1] = __float22bfloat162_rn(float2{p2, p3});
                    *(uint2*)&Pl[w][mb][ql][kk * 16 + quad * 4] = pu.u;
                }
                rsum += __shfl_xor(rsum, 16);
                rsum += __shfl_xor(rsum, 32);

                if (skip) {
                    l_[mb] += rsum;
                    alpha_[mb] = 1.f; resc_[mb] = false;
                } else {
                    const float al = __builtin_amdgcn_exp2f(m_[mb] - mnew);
                    l_[mb] = l_[mb] * al + rsum;
                    m_[mb] = mnew;
                    alpha_[mb] = al; resc_[mb] = true;
                }
            }

            // ---- read both pf (mb=1 softmax sat between mb=0's write and this read) ----
            bf16x8 pf0 = *(const bf16x8*)&Pl[w][0][ql][quad * 8];
            bf16x8 pf1 = *(const bf16x8*)&Pl[w][1][ql][quad * 8];

            #pragma unroll
            for (int mb = 0; mb < 2; ++mb) {
                if (resc_[mb]) {   // wave-uniform branch; rare after warm-up
                    #pragma unroll
                    for (int r = 0; r < 4; ++r) {
                        float ar = __shfl(alpha_[mb], quad * 4 + r);
                        #pragma unroll
                        for (int n = 0; n < 8; ++n) acc[mb][n][r] *= ar;
                    }
                }
                const bf16x8 pf = mb ? pf1 : pf0;
                #pragma unroll
                for (int n = 0; n < 8; ++n)
                    acc[mb][n] = __builtin_amdgcn_mfma_f32_16x16x32_bf16(pf, vf[n], acc[mb][n], 0, 0, 0);
            }
        }
    }

    // ---- epilogue: O / l ----
    #pragma unroll
    for (int mb = 0; mb < 2; ++mb) {
        #pragma unroll
        for (int r = 0; r < 4; ++r) {
            float lr = __shfl(l_[mb], quad * 4 + r);
            float il = 1.0f / lr;
            long orow = base + (long)(qw0 + mb * 16 + quad * 4 + r) * DIM;
            #pragma unroll
            for (int n = 0; n < 8; ++n)
                out[orow + n * 16 + ql] = acc[mb][n][r] * il;
        }
    }
}

extern "C" void kernel_launch(void* const* d_in, const int* in_sizes, int n_in,
                              void* d_out, int out_size, void* d_ws, size_t ws_size,
                              hipStream_t stream) {
    const float* k = (const float*)d_in[0];
    const float* q = (const float*)d_in[1];
    const float* v = (const float*)d_in[2];
    float* o = (float*)d_out;

    unsigned short* kb = (unsigned short*)d_ws;
    unsigned short* vt = kb + (size_t)BHN * SEQ * DIM;

    cvt_kv<<<dim3(SEQ / 64, BHN), dim3(256), 0, stream>>>(k, v, kb, vt);

    attn_fwd<<<dim3(NXB * BHN), dim3(256), 0, stream>>>(q, kb, vt, o);
}

// Round 4
// 345.509 us; speedup vs baseline: 2.2843x; 1.0200x over previous
//
#include <hip/hip_runtime.h>
#include <hip/hip_bf16.h>
#include <math.h>

#define BATCH 4
#define HEADS 16
#define SEQ   2048
#define DIM   128
#define BHN   (BATCH*HEADS)

#define BQ 128   // q rows per block
#define WQ 32    // q rows per wave (2 MFMA M-blocks)
#define KT 32    // k rows per compute tile (staged in PAIRS: 1 barrier / 2 tiles)
#define NXB (SEQ/BQ)   // 16 q-blocks per bh

typedef short bf16x8 __attribute__((ext_vector_type(8)));
typedef float f32x4  __attribute__((ext_vector_type(4)));

static __device__ __forceinline__ unsigned short f2bf(float f) {
    union { float f; unsigned u; } x; x.f = f;
    unsigned r = x.u + 0x7FFF + ((x.u >> 16) & 1);  // RNE
    return (unsigned short)(r >> 16);
}

// async 16B global -> LDS (no data VGPRs; LDS dest = wave-uniform base + lane*16)
static __device__ __forceinline__ void async_cp16(const unsigned short* g, unsigned short* l) {
    __builtin_amdgcn_global_load_lds(
        (const __attribute__((address_space(1))) unsigned int*)g,
        (__attribute__((address_space(3))) unsigned int*)l,
        16, 0, 0);
}

// ------------- fused fp32->bf16: K row-major, V transposed vt[bh][d][s] -------------
__global__ __launch_bounds__(256) void cvt_kv(
    const float* __restrict__ k, const float* __restrict__ v,
    unsigned short* __restrict__ kb, unsigned short* __restrict__ vt) {
    __shared__ unsigned short T[DIM][72];   // 64 s-rows transposed; 144B row stride
    const int bh = blockIdx.y;
    const int s0 = blockIdx.x * 64;
    const int t  = threadIdx.x;
    const long rbase = ((long)bh * SEQ + s0) * DIM;

    // K: 64 rows x 128 = 8192 elems, 32/thread
    #pragma unroll
    for (int u = 0; u < 2; ++u) {
        long e = rbase + (long)(t + u * 256) * 16;
        const float* src = k + e;
        unsigned short* dst = kb + e;
        #pragma unroll
        for (int h = 0; h < 2; ++h) {
            float4 a0 = *(const float4*)(src + h * 8);
            float4 a1 = *(const float4*)(src + h * 8 + 4);
            union { uint4 u4; unsigned short s[8]; } p;
            p.s[0]=f2bf(a0.x); p.s[1]=f2bf(a0.y); p.s[2]=f2bf(a0.z); p.s[3]=f2bf(a0.w);
            p.s[4]=f2bf(a1.x); p.s[5]=f2bf(a1.y); p.s[6]=f2bf(a1.z); p.s[7]=f2bf(a1.w);
            *(uint4*)(dst + h * 8) = p.u4;
        }
    }
    // V: stage transposed through LDS
    {
        const int r = t >> 2, i = t & 3;
        const float* src = v + rbase + (long)r * DIM + i * 32;
        #pragma unroll
        for (int j = 0; j < 8; ++j) {
            float4 x = *(const float4*)(src + j * 4);
            const int d = i * 32 + j * 4;
            T[d + 0][r] = f2bf(x.x); T[d + 1][r] = f2bf(x.y);
            T[d + 2][r] = f2bf(x.z); T[d + 3][r] = f2bf(x.w);
        }
    }
    __syncthreads();
    {
        const int d = t >> 1, h = t & 1;
        unsigned short* dst = vt + ((long)bh * DIM + d) * SEQ + s0 + h * 32;
        #pragma unroll
        for (int m = 0; m < 4; ++m)
            *(uint4*)(dst + m * 8) = *(const uint4*)&T[d][h * 32 + m * 8];
    }
}

// ---------------- flash attention ----------------
// __launch_bounds__(256, 2): reg footprint ~170 (VGPR+AGPR unified). (256,4)
// spilled 1.6 GB/dispatch (R1) — don't raise. LDS 75776 B -> 2 blocks/CU.
// Pair-staged K-loop: 1 __syncthreads per 2 tiles; the vmcnt(0) drain at the
// barrier targets loads issued ~2 tiles of compute earlier (cover > latency).
__global__ __launch_bounds__(256, 2) void attn_fwd(
    const float* __restrict__ qg,
    const unsigned short* __restrict__ kb,
    const unsigned short* __restrict__ vtg,
    float* __restrict__ out) {

    __shared__ unsigned short Kt[2][2][KT][DIM];    // [pairbuf][tile] 4 x 8 KB
    __shared__ unsigned short Vt[2][2][DIM][KT];    // [pairbuf][tile] 4 x 8 KB
    __shared__ unsigned short Pl[4][2][16][KT + 8]; // per-wave, per-mb P tile

    const int tid  = threadIdx.x;
    const int w    = tid >> 6;
    const int lane = tid & 63;
    const int quad = lane >> 4;
    const int ql   = lane & 15;

    // Work-balance + locality swizzle (R2-verified: occ 11.7->18.4%, FETCH -55%)
    const int flat = blockIdx.x;
    const int xcd  = flat & 7;
    const int slot = flat >> 3;
    const int bh   = (xcd << 3) | (slot & 7);
    const int shi  = slot >> 3;
    // xbmap = {15,14,13,12, 0,1,2,3, 8,9,10,11, 7,6,5,4}: residue classes sum to 30
    const int xb   = (shi < 4) ? (15 - shi)
                   : (shi < 8) ? (shi - 4)
                   : (shi < 12) ? shi
                   : (19 - shi);
    const int qb0 = xb * BQ;
    const int qw0 = qb0 + w * WQ;

    const long base = (long)bh * SEQ * DIM;
    // exp2 domain: log2(e) folded into Q scale; p = exp2(s' - m') via v_exp_f32.
    const float scale = 0.08838834764831845f * 1.4426950408889634f;

    // ---- Q fragments (B-operand for Sc = K*Q^T), pre-scaled ----
    bf16x8 qf[2][4];
    #pragma unroll
    for (int mb = 0; mb < 2; ++mb) {
        const float* qr = qg + base + (long)(qw0 + mb * 16 + ql) * DIM;
        #pragma unroll
        for (int c = 0; c < 4; ++c) {
            const float* p = qr + c * 32 + quad * 8;
            float4 x = *(const float4*)(p);
            float4 y = *(const float4*)(p + 4);
            union { bf16x8 v; unsigned short s[8]; } u;
            u.s[0]=f2bf(x.x*scale); u.s[1]=f2bf(x.y*scale);
            u.s[2]=f2bf(x.z*scale); u.s[3]=f2bf(x.w*scale);
            u.s[4]=f2bf(y.x*scale); u.s[5]=f2bf(y.y*scale);
            u.s[6]=f2bf(y.z*scale); u.s[7]=f2bf(y.w*scale);
            qf[mb][c] = u.v;
        }
    }

    f32x4 acc[2][8];
    #pragma unroll
    for (int mb = 0; mb < 2; ++mb)
        #pragma unroll
        for (int n = 0; n < 8; ++n)
            acc[mb][n] = (f32x4){0.f, 0.f, 0.f, 0.f};

    float m_[2] = {-INFINITY, -INFINITY};
    float l_[2] = {0.f, 0.f};

    // Hoisted staging addresses: swizzle pattern is tid-only; k-advance is a
    // pointer increment (kills per-tile 64-bit address mul for all 8 loads).
    const unsigned short* kap[2];
    const unsigned short* vap[2];
    #pragma unroll
    for (int i = 0; i < 2; ++i) {
        const int idx = tid + i * 256;
        const int r   = idx >> 4;
        const int chg = (idx & 15) ^ (r & 15);
        kap[i] = kb + base + (long)r * DIM + chg * 8;
        const int d   = idx >> 2;
        const int cvg = (idx & 3) ^ ((d >> 1) & 3);
        vap[i] = vtg + base + (long)d * SEQ + cvg * 8;
    }
    const int ldso = ((tid >> 6) * 64) * 8;   // per-thread LDS chunk offset (shorts)

    // stage one KT tile into (pb, ti); advances k-pointers by KT rows
    auto stage = [&](int pb, int ti) {
        #pragma unroll
        for (int i = 0; i < 2; ++i) {
            async_cp16(kap[i], &Kt[pb][ti][0][0] + ldso + i * 2048);
            async_cp16(vap[i], &Vt[pb][ti][0][0] + ldso + i * 2048);
            kap[i] += KT * DIM;
            vap[i] += KT;
        }
    };

    const int ntile = (qb0 + BQ) / KT;   // always a multiple of 4
    const int npair = ntile >> 1;

    stage(0, 0); stage(0, 1);            // pair 0 in flight

    for (int p = 0; p < npair; ++p) {
        const int pb = p & 1;
        __syncthreads();   // drains pair p's loads (issued ~2 tiles of compute ago)

        if (p + 1 < npair) { stage(pb ^ 1, 0); stage(pb ^ 1, 1); }  // pair p+1 in flight

        #pragma unroll
        for (int ti = 0; ti < 2; ++ti) {
            const int k0 = (2 * p + ti) * KT;
            const bool active = (k0 < qw0 + WQ);
            if (!active) continue;

            // ---- Sc = K * Q^T  (rows=k, cols=q) ----
            f32x4 sacc[2][2];
            #pragma unroll
            for (int mb = 0; mb < 2; ++mb)
                #pragma unroll
                for (int kk = 0; kk < 2; ++kk)
                    sacc[mb][kk] = (f32x4){0.f, 0.f, 0.f, 0.f};
            __builtin_amdgcn_s_setprio(1);
            #pragma unroll
            for (int c = 0; c < 4; ++c) {
                const int sw = ((c * 4 + quad) ^ ql) * 8;   // swizzled chunk offset
                bf16x8 kf0 = *(const bf16x8*)&Kt[pb][ti][ql]     [sw];
                bf16x8 kf1 = *(const bf16x8*)&Kt[pb][ti][16 + ql][sw];
                #pragma unroll
                for (int mb = 0; mb < 2; ++mb) {
                    sacc[mb][0] = __builtin_amdgcn_mfma_f32_16x16x32_bf16(kf0, qf[mb][c], sacc[mb][0], 0, 0, 0);
                    sacc[mb][1] = __builtin_amdgcn_mfma_f32_16x16x32_bf16(kf1, qf[mb][c], sacc[mb][1], 0, 0, 0);
                }
            }
            __builtin_amdgcn_s_setprio(0);

            // V fragments (swizzled)
            bf16x8 vf[8];
            #pragma unroll
            for (int n = 0; n < 8; ++n)
                vf[n] = *(const bf16x8*)&Vt[pb][ti][n * 16 + ql][(quad ^ ((ql >> 1) & 3)) * 8];

            // ---- softmax both mb, write both P tiles (defer-max, exp2 domain) ----
            float alpha_[2];
            bool  resc_[2];
            #pragma unroll
            for (int mb = 0; mb < 2; ++mb) {
                const int qrow   = qw0 + mb * 16 + ql;
                const bool needm = (k0 + KT - 1 > qw0 + mb * 16);  // wave-uniform
                float s[2][4];
                float tmax = -INFINITY;
                #pragma unroll
                for (int kk = 0; kk < 2; ++kk)
                    #pragma unroll
                    for (int r = 0; r < 4; ++r) {
                        float sv = sacc[mb][kk][r];
                        if (needm) {
                            int kg = k0 + kk * 16 + quad * 4 + r;
                            sv = (kg <= qrow) ? sv : -INFINITY;
                        }
                        s[kk][r] = sv;
                        tmax = fmaxf(tmax, sv);
                    }
                tmax = fmaxf(tmax, __shfl_xor(tmax, 16));
                tmax = fmaxf(tmax, __shfl_xor(tmax, 32));

                // T13 defer-max, THR=4 (log2 units): P bounded by 2^4=16 -> keeps
                // bf16 P error small (R3's THR=8 pushed absmax to 0.0300).
                const bool skip = __all(tmax <= m_[mb] + 4.0f);
                const float mnew = skip ? m_[mb] : fmaxf(m_[mb], tmax);

                float rsum = 0.f;
                #pragma unroll
                for (int kk = 0; kk < 2; ++kk) {
                    float p0 = __builtin_amdgcn_exp2f(s[kk][0] - mnew);
                    float p1 = __builtin_amdgcn_exp2f(s[kk][1] - mnew);
                    float p2 = __builtin_amdgcn_exp2f(s[kk][2] - mnew);
                    float p3 = __builtin_amdgcn_exp2f(s[kk][3] - mnew);
                    rsum += (p0 + p1) + (p2 + p3);
                    union { uint2 u; __hip_bfloat162 h[2]; } pu;   // v_cvt_pk_bf16_f32
                    pu.h[0] = __float22bfloat162_rn(float2{p0, p1});
                    pu.h[1] = __float22bfloat162_rn(float2{p2, p3});
                    *(uint2*)&Pl[w][mb][ql][kk * 16 + quad * 4] = pu.u;
                }
                rsum += __shfl_xor(rsum, 16);
                rsum += __shfl_xor(rsum, 32);

                if (skip) {
                    l_[mb] += rsum;
                    alpha_[mb] = 1.f; resc_[mb] = false;
                } else {
                    const float al = __builtin_amdgcn_exp2f(m_[mb] - mnew);
                    l_[mb] = l_[mb] * al + rsum;
                    m_[mb] = mnew;
                    alpha_[mb] = al; resc_[mb] = true;
                }
            }

            // ---- read both pf (mb=1 softmax hides mb=0's ds_write->read lgkm) ----
            bf16x8 pf0 = *(const bf16x8*)&Pl[w][0][ql][quad * 8];
            bf16x8 pf1 = *(const bf16x8*)&Pl[w][1][ql][quad * 8];

            #pragma unroll
            for (int mb = 0; mb < 2; ++mb) {
                if (resc_[mb]) {   // wave-uniform; rare after warm-up
                    #pragma unroll
                    for (int r = 0; r < 4; ++r) {
                        float ar = __shfl(alpha_[mb], quad * 4 + r);
                        #pragma unroll
                        for (int n = 0; n < 8; ++n) acc[mb][n][r] *= ar;
                    }
                }
                const bf16x8 pf = mb ? pf1 : pf0;
                __builtin_amdgcn_s_setprio(1);
                #pragma unroll
                for (int n = 0; n < 8; ++n)
                    acc[mb][n] = __builtin_amdgcn_mfma_f32_16x16x32_bf16(pf, vf[n], acc[mb][n], 0, 0, 0);
                __builtin_amdgcn_s_setprio(0);
            }
        }
    }

    // ---- epilogue: O / l ----
    #pragma unroll
    for (int mb = 0; mb < 2; ++mb) {
        #pragma unroll
        for (int r = 0; r < 4; ++r) {
            float lr = __shfl(l_[mb], quad * 4 + r);
            float il = 1.0f / lr;
            long orow = base + (long)(qw0 + mb * 16 + quad * 4 + r) * DIM;
            #pragma unroll
            for (int n = 0; n < 8; ++n)
                out[orow + n * 16 + ql] = acc[mb][n][r] * il;
        }
    }
}

extern "C" void kernel_launch(void* const* d_in, const int* in_sizes, int n_in,
                              void* d_out, int out_size, void* d_ws, size_t ws_size,
                              hipStream_t stream) {
    const float* k = (const float*)d_in[0];
    const float* q = (const float*)d_in[1];
    const float* v = (const float*)d_in[2];
    float* o = (float*)d_out;

    unsigned short* kb = (unsigned short*)d_ws;
    unsigned short* vt = kb + (size_t)BHN * SEQ * DIM;

    cvt_kv<<<dim3(SEQ / 64, BHN), dim3(256), 0, stream>>>(k, v, kb, vt);

    attn_fwd<<<dim3(NXB * BHN), dim3(256), 0, stream>>>(q, kb, vt, o);
}

// Round 5
// 328.568 us; speedup vs baseline: 2.4020x; 1.0516x over previous
//
#include <hip/hip_runtime.h>
#include <hip/hip_bf16.h>
#include <math.h>

#define BATCH 4
#define HEADS 16
#define SEQ   2048
#define DIM   128
#define BHN   (BATCH*HEADS)

#define BQ 64    // q rows per block (4 waves x WQ=16)
#define WQ 16    // q rows per wave (1 MFMA M-block: halves per-wave regs -> 4 waves/SIMD)
#define KT 32    // k rows per stage/compute tile
#define NXB (SEQ/BQ)   // 32 q-blocks per bh

typedef short bf16x8 __attribute__((ext_vector_type(8)));
typedef float f32x4  __attribute__((ext_vector_type(4)));

static __device__ __forceinline__ unsigned short f2bf(float f) {
    union { float f; unsigned u; } x; x.f = f;
    unsigned r = x.u + 0x7FFF + ((x.u >> 16) & 1);  // RNE
    return (unsigned short)(r >> 16);
}

// async 16B global -> LDS (no data VGPRs; LDS dest = wave-uniform base + lane*16)
static __device__ __forceinline__ void async_cp16(const unsigned short* g, unsigned short* l) {
    __builtin_amdgcn_global_load_lds(
        (const __attribute__((address_space(1))) unsigned int*)g,
        (__attribute__((address_space(3))) unsigned int*)l,
        16, 0, 0);
}

// ------------- fused fp32->bf16: K row-major, V transposed vt[bh][d][s] -------------
__global__ __launch_bounds__(256) void cvt_kv(
    const float* __restrict__ k, const float* __restrict__ v,
    unsigned short* __restrict__ kb, unsigned short* __restrict__ vt) {
    __shared__ unsigned short T[DIM][72];   // 64 s-rows transposed; 144B row stride
    const int bh = blockIdx.y;
    const int s0 = blockIdx.x * 64;
    const int t  = threadIdx.x;
    const long rbase = ((long)bh * SEQ + s0) * DIM;

    // K: 64 rows x 128 = 8192 elems, 32/thread
    #pragma unroll
    for (int u = 0; u < 2; ++u) {
        long e = rbase + (long)(t + u * 256) * 16;
        const float* src = k + e;
        unsigned short* dst = kb + e;
        #pragma unroll
        for (int h = 0; h < 2; ++h) {
            float4 a0 = *(const float4*)(src + h * 8);
            float4 a1 = *(const float4*)(src + h * 8 + 4);
            union { uint4 u4; unsigned short s[8]; } p;
            p.s[0]=f2bf(a0.x); p.s[1]=f2bf(a0.y); p.s[2]=f2bf(a0.z); p.s[3]=f2bf(a0.w);
            p.s[4]=f2bf(a1.x); p.s[5]=f2bf(a1.y); p.s[6]=f2bf(a1.z); p.s[7]=f2bf(a1.w);
            *(uint4*)(dst + h * 8) = p.u4;
        }
    }
    // V: stage transposed through LDS
    {
        const int r = t >> 2, i = t & 3;
        const float* src = v + rbase + (long)r * DIM + i * 32;
        #pragma unroll
        for (int j = 0; j < 8; ++j) {
            float4 x = *(const float4*)(src + j * 4);
            const int d = i * 32 + j * 4;
            T[d + 0][r] = f2bf(x.x); T[d + 1][r] = f2bf(x.y);
            T[d + 2][r] = f2bf(x.z); T[d + 3][r] = f2bf(x.w);
        }
    }
    __syncthreads();
    {
        const int d = t >> 1, h = t & 1;
        unsigned short* dst = vt + ((long)bh * DIM + d) * SEQ + s0 + h * 32;
        #pragma unroll
        for (int m = 0; m < 4; ++m)
            *(uint4*)(dst + m * 8) = *(const uint4*)&T[d][h * 32 + m * 8];
    }
}

// ---------------- flash attention ----------------
// WQ=16: per-wave regs ~110-120 (acc 32 + qf 16 + vf 32 transient + misc) ->
// __launch_bounds__(256,4) caps at 128 without spill (R1 spilled because the
// WQ=32 footprint was 164 >> 128; this one is estimated under the cap).
// LDS 37888 B -> 4 blocks/CU; 4 barrier-INDEPENDENT blocks = 16 waves/CU is the
// latency-hiding R3/R4 lacked. Tripwire: WRITE_SIZE > ~80 MB => spill => (256,3).
__global__ __launch_bounds__(256, 4) void attn_fwd(
    const float* __restrict__ qg,
    const unsigned short* __restrict__ kb,
    const unsigned short* __restrict__ vtg,
    float* __restrict__ out) {

    __shared__ unsigned short Kt[2][KT][DIM];    // 2 x 32 x 128 (8 KB each)
    __shared__ unsigned short Vt[2][DIM][KT];    // 2 x 128 x 32 (8 KB each)
    __shared__ unsigned short Pl[4][16][KT + 8]; // per-wave P tile [q][k] (5 KB)

    const int tid  = threadIdx.x;
    const int w    = tid >> 6;
    const int lane = tid & 63;
    const int quad = lane >> 4;
    const int ql   = lane & 15;

    // Work-balance + locality swizzle, 2048 blocks:
    //   xcd = flat&7, bh = xcd*8 + slot%8  -> bh fixed along a CU's block sequence
    //   shi = slot>>3 in [0,32); class c = shi&3 is shared by co-residents
    //   (flat spacing 256). Class c = {31-c, 24+c, 23-c, 16+c, 15-c, 8+c, 7-c, c}
    //   sums to 124 for every c -> each CU runs exactly 264 tile-iters.
    //   Heavy (diagonal) blocks first within each class.
    const int flat = blockIdx.x;
    const int xcd  = flat & 7;
    const int slot = flat >> 3;
    const int bh   = (xcd << 3) | (slot & 7);
    const int shi  = slot >> 3;
    const int c_   = shi & 3;
    const int j_   = shi >> 2;
    const int xb   = (j_ & 1) ? (28 + c_ - 4 * j_) : (31 - c_ - 4 * j_);
    const int qb0 = xb * BQ;
    const int qw0 = qb0 + w * WQ;

    const long base = (long)bh * SEQ * DIM;
    // exp2 domain: log2(e) folded into Q scale; p = exp2(s' - m') via v_exp_f32.
    const float scale = 0.08838834764831845f * 1.4426950408889634f;

    // ---- Q fragments (B-operand for Sc = K*Q^T), pre-scaled; one 16-row M-block ----
    bf16x8 qf[4];
    {
        const float* qr = qg + base + (long)(qw0 + ql) * DIM;
        #pragma unroll
        for (int c = 0; c < 4; ++c) {
            const float* p = qr + c * 32 + quad * 8;
            float4 x = *(const float4*)(p);
            float4 y = *(const float4*)(p + 4);
            union { bf16x8 v; unsigned short s[8]; } u;
            u.s[0]=f2bf(x.x*scale); u.s[1]=f2bf(x.y*scale);
            u.s[2]=f2bf(x.z*scale); u.s[3]=f2bf(x.w*scale);
            u.s[4]=f2bf(y.x*scale); u.s[5]=f2bf(y.y*scale);
            u.s[6]=f2bf(y.z*scale); u.s[7]=f2bf(y.w*scale);
            qf[c] = u.v;
        }
    }

    f32x4 acc[8];
    #pragma unroll
    for (int n = 0; n < 8; ++n) acc[n] = (f32x4){0.f, 0.f, 0.f, 0.f};

    float m_ = -INFINITY;
    float l_ = 0.f;

    // Hoisted staging addresses (swizzle is tid-only; k-advance = pointer add).
    const unsigned short* kap[2];
    const unsigned short* vap[2];
    #pragma unroll
    for (int i = 0; i < 2; ++i) {
        const int idx = tid + i * 256;
        const int r   = idx >> 4;
        const int chg = (idx & 15) ^ (r & 15);
        kap[i] = kb + base + (long)r * DIM + chg * 8;
        const int d   = idx >> 2;
        const int cvg = (idx & 3) ^ ((d >> 1) & 3);
        vap[i] = vtg + base + (long)d * SEQ + cvg * 8;
    }
    const int ldso = ((tid >> 6) * 64) * 8;   // per-thread LDS chunk offset (shorts)

    auto stage = [&](int buf) {
        #pragma unroll
        for (int i = 0; i < 2; ++i) {
            async_cp16(kap[i], &Kt[buf][0][0] + ldso + i * 2048);
            async_cp16(vap[i], &Vt[buf][0][0] + ldso + i * 2048);
            kap[i] += KT * DIM;
            vap[i] += KT;
        }
    };

    const int ntile = 2 * xb + 2;   // (qb0 + BQ) / KT

    stage(0);

    for (int t = 0; t < ntile; ++t) {
        const int buf = t & 1;
        const int k0  = t * KT;
        __syncthreads();   // tile t resident; prior readers of other buf done

        if (t + 1 < ntile) stage(buf ^ 1);   // in flight during compute of tile t

        if (k0 >= qw0 + WQ) continue;        // inactive wave: straight to next barrier

        // ---- Sc = K * Q^T  (rows=k, cols=q) ----
        f32x4 sacc[2];
        sacc[0] = (f32x4){0.f, 0.f, 0.f, 0.f};
        sacc[1] = (f32x4){0.f, 0.f, 0.f, 0.f};
        __builtin_amdgcn_s_setprio(1);
        #pragma unroll
        for (int c = 0; c < 4; ++c) {
            const int sw = ((c * 4 + quad) ^ ql) * 8;   // swizzled chunk offset
            bf16x8 kf0 = *(const bf16x8*)&Kt[buf][ql]     [sw];
            bf16x8 kf1 = *(const bf16x8*)&Kt[buf][16 + ql][sw];
            sacc[0] = __builtin_amdgcn_mfma_f32_16x16x32_bf16(kf0, qf[c], sacc[0], 0, 0, 0);
            sacc[1] = __builtin_amdgcn_mfma_f32_16x16x32_bf16(kf1, qf[c], sacc[1], 0, 0, 0);
        }
        __builtin_amdgcn_s_setprio(0);

        // V fragments (swizzled) — loaded before softmax so lgkm hides under VALU
        bf16x8 vf[8];
        #pragma unroll
        for (int n = 0; n < 8; ++n)
            vf[n] = *(const bf16x8*)&Vt[buf][n * 16 + ql][(quad ^ ((ql >> 1) & 3)) * 8];

        // ---- softmax (defer-max THR=4, exp2 domain) ----
        const int qrow   = qw0 + ql;
        const bool needm = (k0 + KT - 1 > qw0);  // wave-uniform
        float s[2][4];
        float tmax = -INFINITY;
        #pragma unroll
        for (int kk = 0; kk < 2; ++kk)
            #pragma unroll
            for (int r = 0; r < 4; ++r) {
                float sv = sacc[kk][r];
                if (needm) {
                    int kg = k0 + kk * 16 + quad * 4 + r;
                    sv = (kg <= qrow) ? sv : -INFINITY;
                }
                s[kk][r] = sv;
                tmax = fmaxf(tmax, sv);
            }
        tmax = fmaxf(tmax, __shfl_xor(tmax, 16));
        tmax = fmaxf(tmax, __shfl_xor(tmax, 32));

        // T13 defer-max: P bounded by 2^4=16 (bf16-safe; THR=8 hurt absmax in R3).
        const bool skip = __all(tmax <= m_ + 4.0f);
        const float mnew = skip ? m_ : fmaxf(m_, tmax);

        float rsum = 0.f;
        #pragma unroll
        for (int kk = 0; kk < 2; ++kk) {
            float p0 = __builtin_amdgcn_exp2f(s[kk][0] - mnew);
            float p1 = __builtin_amdgcn_exp2f(s[kk][1] - mnew);
            float p2 = __builtin_amdgcn_exp2f(s[kk][2] - mnew);
            float p3 = __builtin_amdgcn_exp2f(s[kk][3] - mnew);
            rsum += (p0 + p1) + (p2 + p3);
            union { uint2 u; __hip_bfloat162 h[2]; } pu;   // v_cvt_pk_bf16_f32
            pu.h[0] = __float22bfloat162_rn(float2{p0, p1});
            pu.h[1] = __float22bfloat162_rn(float2{p2, p3});
            *(uint2*)&Pl[w][ql][kk * 16 + quad * 4] = pu.u;
        }
        rsum += __shfl_xor(rsum, 16);
        rsum += __shfl_xor(rsum, 32);

        float alpha;
        bool  resc;
        if (skip) {
            l_ += rsum;
            alpha = 1.f; resc = false;
        } else {
            alpha = __builtin_amdgcn_exp2f(m_ - mnew);
            l_ = l_ * alpha + rsum;
            m_ = mnew;
            resc = true;
        }

        if (resc) {   // wave-uniform; rare after warm-up
            #pragma unroll
            for (int r = 0; r < 4; ++r) {
                float ar = __shfl(alpha, quad * 4 + r);
                #pragma unroll
                for (int n = 0; n < 8; ++n) acc[n][r] *= ar;
            }
        }

        // P fragment (A-operand: row=ql? no — row=lane&15, k=quad*8+j)
        bf16x8 pf = *(const bf16x8*)&Pl[w][ql][quad * 8];
        __builtin_amdgcn_s_setprio(1);
        #pragma unroll
        for (int n = 0; n < 8; ++n)
            acc[n] = __builtin_amdgcn_mfma_f32_16x16x32_bf16(pf, vf[n], acc[n], 0, 0, 0);
        __builtin_amdgcn_s_setprio(0);
    }

    // ---- epilogue: O / l ----
    #pragma unroll
    for (int r = 0; r < 4; ++r) {
        float lr = __shfl(l_, quad * 4 + r);
        float il = 1.0f / lr;
        long orow = base + (long)(qw0 + quad * 4 + r) * DIM;
        #pragma unroll
        for (int n = 0; n < 8; ++n)
            out[orow + n * 16 + ql] = acc[n][r] * il;
    }
}

extern "C" void kernel_launch(void* const* d_in, const int* in_sizes, int n_in,
                              void* d_out, int out_size, void* d_ws, size_t ws_size,
                              hipStream_t stream) {
    const float* k = (const float*)d_in[0];
    const float* q = (const float*)d_in[1];
    const float* v = (const float*)d_in[2];
    float* o = (float*)d_out;

    unsigned short* kb = (unsigned short*)d_ws;
    unsigned short* vt = kb + (size_t)BHN * SEQ * DIM;

    cvt_kv<<<dim3(SEQ / 64, BHN), dim3(256), 0, stream>>>(k, v, kb, vt);

    attn_fwd<<<dim3(NXB * BHN), dim3(256), 0, stream>>>(q, kb, vt, o);
}

// Round 6
// 321.801 us; speedup vs baseline: 2.4525x; 1.0210x over previous
//
#include <hip/hip_runtime.h>
#include <hip/hip_bf16.h>
#include <math.h>

#define BATCH 4
#define HEADS 16
#define SEQ   2048
#define DIM   128
#define BHN   (BATCH*HEADS)

#define BQ 64    // q rows per block (4 waves x WQ=16)
#define WQ 16    // q rows per wave (1 MFMA M-block)
#define KT 32    // k rows per stage/compute tile
#define NXB (SEQ/BQ)   // 32 q-blocks per bh

typedef short bf16x8 __attribute__((ext_vector_type(8)));
typedef float f32x4  __attribute__((ext_vector_type(4)));

static __device__ __forceinline__ unsigned short f2bf(float f) {
    union { float f; unsigned u; } x; x.f = f;
    unsigned r = x.u + 0x7FFF + ((x.u >> 16) & 1);  // RNE
    return (unsigned short)(r >> 16);
}

// async 16B global -> LDS (no data VGPRs; LDS dest = wave-uniform base + lane*16)
static __device__ __forceinline__ void async_cp16(const unsigned short* g, unsigned short* l) {
    __builtin_amdgcn_global_load_lds(
        (const __attribute__((address_space(1))) unsigned int*)g,
        (__attribute__((address_space(3))) unsigned int*)l,
        16, 0, 0);
}

// ------------- fused fp32->bf16: K row-major, V^T via in-register transpose -------------
// LDS-free rewrite: old version staged V through LDS with 32 scalar ds_write_b16
// per thread (8-way bank conflicts — the constant 3.19M SQ_LDS_BANK_CONFLICT seen
// in R0-R5) + barrier + readout pass. New V path: each thread owns a 4s x 8d
// micro-tile, transposes in registers, writes ushort4 directly to vt.
// Both sides move >=128B contiguous per 16-lane group. Pure streaming kernel.
__global__ __launch_bounds__(256) void cvt_kv(
    const float* __restrict__ k, const float* __restrict__ v,
    unsigned short* __restrict__ kb, unsigned short* __restrict__ vt) {
    const int bh = blockIdx.y;
    const int s0 = blockIdx.x * 64;
    const int t  = threadIdx.x;
    const long rbase = ((long)bh * SEQ + s0) * DIM;

    // K: 64 rows x 128 = 8192 elems, 32/thread, packed converts
    #pragma unroll
    for (int u = 0; u < 2; ++u) {
        long e = rbase + (long)(t + u * 256) * 16;
        const float* src = k + e;
        unsigned short* dst = kb + e;
        #pragma unroll
        for (int h = 0; h < 2; ++h) {
            float4 a0 = *(const float4*)(src + h * 8);
            float4 a1 = *(const float4*)(src + h * 8 + 4);
            union { uint4 q; __hip_bfloat162 b[4]; } p;
            p.b[0] = __float22bfloat162_rn(float2{a0.x, a0.y});
            p.b[1] = __float22bfloat162_rn(float2{a0.z, a0.w});
            p.b[2] = __float22bfloat162_rn(float2{a1.x, a1.y});
            p.b[3] = __float22bfloat162_rn(float2{a1.z, a1.w});
            *(uint4*)(dst + h * 8) = p.q;
        }
    }
    // V: rg = t&15 (s-rows rg*4..+3), dg = t>>4 (d = dg*8..+7).
    // Read: per rr, 16 rg-lanes cover 128B of each of 4 rows. Write: per dd,
    // 16 rg-lanes write 128B contiguous of each of 4 d-rows.
    {
        const int rg = t & 15;
        const int dg = t >> 4;
        const float* src = v + rbase + (long)(rg * 4) * DIM + dg * 8;
        float a[4][8];
        #pragma unroll
        for (int rr = 0; rr < 4; ++rr) {
            float4 x = *(const float4*)(src + rr * DIM);
            float4 y = *(const float4*)(src + rr * DIM + 4);
            a[rr][0]=x.x; a[rr][1]=x.y; a[rr][2]=x.z; a[rr][3]=x.w;
            a[rr][4]=y.x; a[rr][5]=y.y; a[rr][6]=y.z; a[rr][7]=y.w;
        }
        unsigned short* dstb = vt + ((long)bh * DIM + dg * 8) * SEQ + s0 + rg * 4;
        #pragma unroll
        for (int dd = 0; dd < 8; ++dd) {
            union { uint2 u; __hip_bfloat162 b[2]; } p;
            p.b[0] = __float22bfloat162_rn(float2{a[0][dd], a[1][dd]});
            p.b[1] = __float22bfloat162_rn(float2{a[2][dd], a[3][dd]});
            *(uint2*)(dstb + (long)dd * SEQ) = p.u;
        }
    }
}

// ---------------- flash attention ----------------
// R5-verified: WQ=16 + (256,4) -> VGPR 60, occupancy 38.7%, no spill.
// R6: addressing diet — LDS fragment base pointers hoisted (buf as compile-time
// immediate via x2-unrolled tile loop), staging via uniform base + invariant
// 32-bit lane offsets (saddr form) instead of per-lane 64-bit pointer bumps.
__global__ __launch_bounds__(256, 4) void attn_fwd(
    const float* __restrict__ qg,
    const unsigned short* __restrict__ kb,
    const unsigned short* __restrict__ vtg,
    float* __restrict__ out) {

    __shared__ unsigned short Kt[2][KT][DIM];    // 2 x 32 x 128 (8 KB each)
    __shared__ unsigned short Vt[2][DIM][KT];    // 2 x 128 x 32 (8 KB each)
    __shared__ unsigned short Pl[4][16][KT + 8]; // per-wave P tile [q][k] (5 KB)

    const int tid  = threadIdx.x;
    const int w    = tid >> 6;
    const int lane = tid & 63;
    const int quad = lane >> 4;
    const int ql   = lane & 15;

    // Work-balance + locality swizzle (R5-verified: occ 38.7%, FETCH 88MB):
    // bh fixed along a CU's co-resident blocks; xb classes sum to 124 each.
    const int flat = blockIdx.x;
    const int xcd  = flat & 7;
    const int slot = flat >> 3;
    const int bh   = (xcd << 3) | (slot & 7);
    const int shi  = slot >> 3;
    const int c_   = shi & 3;
    const int j_   = shi >> 2;
    const int xb   = (j_ & 1) ? (28 + c_ - 4 * j_) : (31 - c_ - 4 * j_);
    const int qb0 = xb * BQ;
    const int qw0 = qb0 + w * WQ;

    const long base = (long)bh * SEQ * DIM;
    // exp2 domain: log2(e) folded into Q scale; p = exp2(s' - m') via v_exp_f32.
    const float scale = 0.08838834764831845f * 1.4426950408889634f;

    // ---- Q fragments (B-operand for Sc = K*Q^T), pre-scaled ----
    bf16x8 qf[4];
    {
        const float* qr = qg + base + (long)(qw0 + ql) * DIM;
        #pragma unroll
        for (int c = 0; c < 4; ++c) {
            const float* p = qr + c * 32 + quad * 8;
            float4 x = *(const float4*)(p);
            float4 y = *(const float4*)(p + 4);
            union { bf16x8 v; unsigned short s[8]; } u;
            u.s[0]=f2bf(x.x*scale); u.s[1]=f2bf(x.y*scale);
            u.s[2]=f2bf(x.z*scale); u.s[3]=f2bf(x.w*scale);
            u.s[4]=f2bf(y.x*scale); u.s[5]=f2bf(y.y*scale);
            u.s[6]=f2bf(y.z*scale); u.s[7]=f2bf(y.w*scale);
            qf[c] = u.v;
        }
    }

    f32x4 acc[8];
    #pragma unroll
    for (int n = 0; n < 8; ++n) acc[n] = (f32x4){0.f, 0.f, 0.f, 0.f};

    float m_ = -INFINITY;
    float l_ = 0.f;

    // ---- staging: uniform tile base + loop-invariant lane offsets ----
    int koff[2], voff[2];
    #pragma unroll
    for (int i = 0; i < 2; ++i) {
        const int idx = tid + i * 256;
        const int r   = idx >> 4;
        const int chg = (idx & 15) ^ (r & 15);   // K chunk swizzle
        koff[i] = r * DIM + chg * 8;
        const int d   = idx >> 2;
        const int cvg = (idx & 3) ^ ((d >> 1) & 3);  // V chunk swizzle
        voff[i] = d * SEQ + cvg * 8;
    }
    const int ldso = ((tid >> 6) * 64) * 8;      // wave-uniform LDS chunk offset
    const unsigned short* kbb = kb + base;
    const unsigned short* vbb = vtg + base;

    auto stage = [&](int buf, int k0s) {
        const unsigned short* ku = kbb + k0s * DIM;  // wave-uniform (scalar k0s)
        const unsigned short* vu = vbb + k0s;
        #pragma unroll
        for (int i = 0; i < 2; ++i) {
            async_cp16(ku + koff[i], &Kt[buf][0][0] + ldso + i * 2048);
            async_cp16(vu + voff[i], &Vt[buf][0][0] + ldso + i * 2048);
        }
    };

    // ---- hoisted LDS fragment base pointers (buf folded as immediate) ----
    const unsigned short* kfb[4];
    #pragma unroll
    for (int c = 0; c < 4; ++c)
        kfb[c] = &Kt[0][ql][((c * 4 + quad) ^ ql) * 8];
    const unsigned short* vfb = &Vt[0][0][0] + ql * KT + (quad ^ ((ql >> 1) & 3)) * 8;
    unsigned short* pwb = &Pl[w][ql][0];
    const unsigned short* prb = &Pl[w][ql][quad * 8];

    // one tile's compute; buf is a LITERAL at both call sites -> all LDS
    // accesses become base + immediate offset (no per-tile address VALU)
    auto body = [&](const int buf, const int k0) {
        if (k0 >= qw0 + WQ) return;   // inactive wave: straight to next barrier
        const int kbo = buf * (KT * DIM);   // shorts; folds to ds offset imm
        const int vbo = buf * (DIM * KT);

        f32x4 sacc0 = (f32x4){0.f, 0.f, 0.f, 0.f};
        f32x4 sacc1 = (f32x4){0.f, 0.f, 0.f, 0.f};
        __builtin_amdgcn_s_setprio(1);
        #pragma unroll
        for (int c = 0; c < 4; ++c) {
            bf16x8 kf0 = *(const bf16x8*)(kfb[c] + kbo);
            bf16x8 kf1 = *(const bf16x8*)(kfb[c] + kbo + 16 * DIM);
            sacc0 = __builtin_amdgcn_mfma_f32_16x16x32_bf16(kf0, qf[c], sacc0, 0, 0, 0);
            sacc1 = __builtin_amdgcn_mfma_f32_16x16x32_bf16(kf1, qf[c], sacc1, 0, 0, 0);
        }
        __builtin_amdgcn_s_setprio(0);

        // V fragments (swizzled) — issued before softmax so lgkm hides under VALU
        bf16x8 vf[8];
        #pragma unroll
        for (int n = 0; n < 8; ++n)
            vf[n] = *(const bf16x8*)(vfb + vbo + n * (16 * KT));

        // ---- softmax (defer-max THR=4, exp2 domain) ----
        const int qrow   = qw0 + ql;
        const bool needm = (k0 + KT - 1 > qw0);  // wave-uniform
        float s[2][4];
        float tmax = -INFINITY;
        #pragma unroll
        for (int kk = 0; kk < 2; ++kk)
            #pragma unroll
            for (int r = 0; r < 4; ++r) {
                float sv = (kk ? sacc1 : sacc0)[r];
                if (needm) {
                    int kg = k0 + kk * 16 + quad * 4 + r;
                    sv = (kg <= qrow) ? sv : -INFINITY;
                }
                s[kk][r] = sv;
                tmax = fmaxf(tmax, sv);
            }
        tmax = fmaxf(tmax, __shfl_xor(tmax, 16));
        tmax = fmaxf(tmax, __shfl_xor(tmax, 32));

        // T13 defer-max: P bounded by 2^4=16 (bf16-safe)
        const bool skip = __all(tmax <= m_ + 4.0f);
        const float mnew = skip ? m_ : fmaxf(m_, tmax);

        float rsum = 0.f;
        #pragma unroll
        for (int kk = 0; kk < 2; ++kk) {
            float p0 = __builtin_amdgcn_exp2f(s[kk][0] - mnew);
            float p1 = __builtin_amdgcn_exp2f(s[kk][1] - mnew);
            float p2 = __builtin_amdgcn_exp2f(s[kk][2] - mnew);
            float p3 = __builtin_amdgcn_exp2f(s[kk][3] - mnew);
            rsum += (p0 + p1) + (p2 + p3);
            union { uint2 u; __hip_bfloat162 h[2]; } pu;   // v_cvt_pk_bf16_f32
            pu.h[0] = __float22bfloat162_rn(float2{p0, p1});
            pu.h[1] = __float22bfloat162_rn(float2{p2, p3});
            *(uint2*)(pwb + kk * 16 + quad * 4) = pu.u;
        }
        rsum += __shfl_xor(rsum, 16);
        rsum += __shfl_xor(rsum, 32);

        float alpha;
        bool  resc;
        if (skip) {
            l_ += rsum;
            alpha = 1.f; resc = false;
        } else {
            alpha = __builtin_amdgcn_exp2f(m_ - mnew);
            l_ = l_ * alpha + rsum;
            m_ = mnew;
            resc = true;
        }

        if (resc) {   // wave-uniform; rare after warm-up
            #pragma unroll
            for (int r = 0; r < 4; ++r) {
                float ar = __shfl(alpha, quad * 4 + r);
                #pragma unroll
                for (int n = 0; n < 8; ++n) acc[n][r] *= ar;
            }
        }

        bf16x8 pf = *(const bf16x8*)prb;
        __builtin_amdgcn_s_setprio(1);
        #pragma unroll
        for (int n = 0; n < 8; ++n)
            acc[n] = __builtin_amdgcn_mfma_f32_16x16x32_bf16(pf, vf[n], acc[n], 0, 0, 0);
        __builtin_amdgcn_s_setprio(0);
    };

    const int ntile = 2 * xb + 2;   // always even

    stage(0, 0);

    for (int tt = 0; tt < ntile; tt += 2) {
        __syncthreads();   // tile tt resident; prior readers of buf0 done
        if (tt + 1 < ntile) stage(1, (tt + 1) * KT);
        body(0, tt * KT);

        __syncthreads();   // tile tt+1 resident; prior readers of buf1 done
        if (tt + 2 < ntile) stage(0, (tt + 2) * KT);
        body(1, (tt + 1) * KT);
    }

    // ---- epilogue: O / l ----
    #pragma unroll
    for (int r = 0; r < 4; ++r) {
        float lr = __shfl(l_, quad * 4 + r);
        float il = 1.0f / lr;
        long orow = base + (long)(qw0 + quad * 4 + r) * DIM;
        #pragma unroll
        for (int n = 0; n < 8; ++n)
            out[orow + n * 16 + ql] = acc[n][r] * il;
    }
}

extern "C" void kernel_launch(void* const* d_in, const int* in_sizes, int n_in,
                              void* d_out, int out_size, void* d_ws, size_t ws_size,
                              hipStream_t stream) {
    const float* k = (const float*)d_in[0];
    const float* q = (const float*)d_in[1];
    const float* v = (const float*)d_in[2];
    float* o = (float*)d_out;

    unsigned short* kb = (unsigned short*)d_ws;
    unsigned short* vt = kb + (size_t)BHN * SEQ * DIM;

    cvt_kv<<<dim3(SEQ / 64, BHN), dim3(256), 0, stream>>>(k, v, kb, vt);

    attn_fwd<<<dim3(NXB * BHN), dim3(256), 0, stream>>>(q, kb, vt, o);
}